// Round 11
// baseline (178.795 us; speedup 1.0000x reference)
//
#include <hip/hip_runtime.h>
#include <hip/hip_bf16.h>
#include <math.h>

#define NTOK 2048
#define HID 2048
#define NEXP 8
#define FINT 768
#define TOPK 2

typedef __attribute__((ext_vector_type(8))) short bf16x8;
typedef __attribute__((ext_vector_type(4))) short bf16x4;
typedef __attribute__((ext_vector_type(4))) float f32x4;

static __device__ __forceinline__ unsigned short f2bf(float f) {
    union { float f; unsigned u; } v; v.f = f;
    unsigned r = v.u + 0x7fffu + ((v.u >> 16) & 1u);
    return (unsigned short)(r >> 16);
}

static __device__ __forceinline__ void gl16(const void* g, void* l) {
    __builtin_amdgcn_global_load_lds(
        (const __attribute__((address_space(1))) unsigned int*)g,
        (__attribute__((address_space(3))) unsigned int*)(uintptr_t)l,
        16, 0, 0);
}

// ---------------- workspace layout (bytes) ----------------
// 0       : topk_idx  int[4096]
// 16384   : topk_w    f32[4096]
// 32768   : counts    int[8]
// 32800   : offsets   int[8]
// 33024   : row_token int[4096]
// 49408   : row_w     f32[4096]
// 65792   : elist_t   int[8*2048]
// 131328  : elist_w   f32[8*2048]
// 196864  : x_bf16    [2048][2048]        8388608
// 58917120: wd_t      [8][2048][768] bf16 25165824   (wg_t/wu_t slots unused now)
// 84082944: h_buf     [4224][768]    bf16 6488064

// ---------------- transpose tile body (wd only now) ----------------
static __device__ __forceinline__ void transpose_tile(
        const float* __restrict__ src, unsigned short* __restrict__ dst,
        int R, int C, int r0, int c0, float* tile, int tid) {
    {
        int rbase = tid >> 4;
        int ch = tid & 15;
        #pragma unroll
        for (int i = 0; i < 4; ++i) {
            int row = i * 16 + rbase;
            float4 v = *(const float4*)&src[(size_t)(r0 + row) * C + c0 + ch * 4];
            int p = ch ^ (row & 15);
            *(float4*)&tile[row * 64 + p * 4] = v;
        }
    }
    __syncthreads();
    {
        int r16 = (tid & 15) * 4;
        int cg = tid >> 4;
        float4 v[4];
        #pragma unroll
        for (int j = 0; j < 4; ++j) {
            int row = r16 + j;
            int p = cg ^ (row & 15);
            v[j] = *(const float4*)&tile[row * 64 + p * 4];
        }
        #pragma unroll
        for (int i = 0; i < 4; ++i) {
            float c0v = (i == 0) ? v[0].x : (i == 1) ? v[0].y : (i == 2) ? v[0].z : v[0].w;
            float c1v = (i == 0) ? v[1].x : (i == 1) ? v[1].y : (i == 2) ? v[1].z : v[1].w;
            float c2v = (i == 0) ? v[2].x : (i == 1) ? v[2].y : (i == 2) ? v[2].z : v[2].w;
            float c3v = (i == 0) ? v[3].x : (i == 1) ? v[3].y : (i == 2) ? v[3].z : v[3].w;
            ushort4 o = make_ushort4(f2bf(c0v), f2bf(c1v), f2bf(c2v), f2bf(c3v));
            *(uint2*)&dst[(size_t)(c0 + cg * 4 + i) * R + r0 + r16] = *(const uint2*)&o;
        }
    }
}

// ---------------- K1: router + x-cvt + out-zero  UNION  wd transpose ------
__global__ __launch_bounds__(256) void k1_router_wd(
        const float* __restrict__ x,
        const float* __restrict__ gw,
        const float* __restrict__ wd,
        float* __restrict__ out,
        float* __restrict__ logits_out,
        int* __restrict__ topk_idx,
        float* __restrict__ topk_w,
        unsigned short* __restrict__ xb,
        unsigned short* __restrict__ wdt) {
    __shared__ __align__(16) float tile[64 * 64];
    int bid = blockIdx.x;
    if (bid < 512) {
        int w = threadIdx.x >> 6, l = threadIdx.x & 63;
        int t = bid * 4 + w;
        const float4* xr = (const float4*)(x + (size_t)t * HID);
        unsigned short* xbr = xb + (size_t)t * HID;
        float4 v[8];
        #pragma unroll
        for (int i = 0; i < 8; ++i) v[i] = xr[i * 64 + l];
        #pragma unroll
        for (int i = 0; i < 8; ++i)
            *(ushort4*)&xbr[(i * 64 + l) * 4] =
                make_ushort4(f2bf(v[i].x), f2bf(v[i].y), f2bf(v[i].z), f2bf(v[i].w));
        {
            float4 z = make_float4(0.f, 0.f, 0.f, 0.f);
            float4* orow = (float4*)(out + (size_t)t * HID);
            #pragma unroll
            for (int i = 0; i < 8; ++i) orow[i * 64 + l] = z;
        }
        float acc[NEXP];
        #pragma unroll
        for (int e = 0; e < NEXP; ++e) {
            const float4* gr = (const float4*)(gw + (size_t)e * HID);
            float a = 0.f;
            #pragma unroll
            for (int i = 0; i < 8; ++i) {
                float4 g = gr[i * 64 + l];
                a += v[i].x * g.x + v[i].y * g.y + v[i].z * g.z + v[i].w * g.w;
            }
            acc[e] = a;
        }
        #pragma unroll
        for (int off = 32; off > 0; off >>= 1)
            #pragma unroll
            for (int e = 0; e < NEXP; ++e) acc[e] += __shfl_xor(acc[e], off);
        if (l == 0) {
            float m = -1e30f;
            #pragma unroll
            for (int i = 0; i < NEXP; ++i) m = fmaxf(m, acc[i]);
            float p[NEXP];
            #pragma unroll
            for (int i = 0; i < NEXP; ++i) p[i] = expf(acc[i] - m);
            int i0 = 0;
            #pragma unroll
            for (int i = 1; i < NEXP; ++i) if (p[i] > p[i0]) i0 = i;
            int i1 = (i0 == 0) ? 1 : 0;
            #pragma unroll
            for (int i = 0; i < NEXP; ++i) if (i != i0 && p[i] > p[i1]) i1 = i;
            float w0 = p[i0], w1 = p[i1], sw = w0 + w1;
            topk_idx[t * 2 + 0] = i0;
            topk_idx[t * 2 + 1] = i1;
            topk_w[t * 2 + 0] = w0 / sw;
            topk_w[t * 2 + 1] = w1 / sw;
            #pragma unroll
            for (int i = 0; i < NEXP; ++i) logits_out[(size_t)t * NEXP + i] = acc[i];
        }
    } else {
        int idx = bid - 512;            // 0..3071
        int e = idx / 384, sub = idx % 384;
        int tr = sub / 32, tc = sub % 32;   // wd [768][2048]: 12 x 32 tiles
        transpose_tile(wd + (size_t)e * FINT * HID,
                       wdt + (size_t)e * FINT * HID,
                       FINT, HID, tr * 64, tc * 64, tile, threadIdx.x);
    }
}

__global__ void moe_build_kernel(const int* __restrict__ topk_idx,
                                 const float* __restrict__ topk_w,
                                 int* __restrict__ counts,
                                 int* __restrict__ offsets,
                                 int* __restrict__ elist_t,
                                 float* __restrict__ elist_w,
                                 int* __restrict__ row_token,
                                 float* __restrict__ row_w) {
    __shared__ int scnt[NEXP];
    __shared__ int soff[NEXP];
    int tid = threadIdx.x; // 1024
    if (tid < NEXP) scnt[tid] = 0;
    __syncthreads();
    for (int t = tid; t < NTOK; t += 1024) {
        #pragma unroll
        for (int k = 0; k < TOPK; ++k) {
            int e = topk_idx[t * 2 + k];
            float w = topk_w[t * 2 + k];
            int slot = atomicAdd(&scnt[e], 1);
            elist_t[e * NTOK + slot] = t;
            elist_w[e * NTOK + slot] = w;
        }
    }
    __syncthreads();
    if (tid == 0) {
        int o = 0;
        for (int e = 0; e < NEXP; ++e) {
            soff[e] = o; offsets[e] = o; counts[e] = scnt[e]; o += scnt[e];
        }
    }
    __syncthreads();
    for (int e = 0; e < NEXP; ++e) {
        int c = scnt[e], o = soff[e];
        for (int s = tid; s < c; s += 1024) {
            row_token[o + s] = elist_t[e * NTOK + s];
            row_w[o + s]     = elist_w[e * NTOK + s];
        }
    }
}

// ---------------- MFMA stage A (fused weight conversion) ----------------
// h = silu(x*Wg) * (x*Wu).  64x64 tile, BK=64, 4 waves 2x2, dbuf.
// A (xb bf16): gl16 path, 128B XOR-swizzled rows (unchanged, verified).
// B (wg/wu f32 natural [k][n]): reg-staged micro-tile 4k x 4n per thread:
//   4 coalesced float4 row-loads -> in-reg transpose + f2bf -> 4 ds_write_b64
//   into [64n] rows of 136B (64k bf16 + 8B pad).  Pad makes b64 column reads
//   conflict-free; writes are 4-way (1.58x, m136).  T14 split: loads issue
//   before COMPUTE, LDS writes after.
__global__ __launch_bounds__(256) void moe_stage_a2(
        const unsigned short* __restrict__ xb,    // [2048][2048] bf16
        const float* __restrict__ wg,             // [8][2048][768] f32
        const float* __restrict__ wu,             // [8][2048][768] f32
        const int* __restrict__ counts,
        const int* __restrict__ offsets,
        const int* __restrict__ row_token,
        unsigned short* __restrict__ h_buf) {     // [4224][768]
    int e = blockIdx.x, mt = blockIdx.y, nt = blockIdx.z;
    int count = counts[e];
    int m0 = mt * 64;
    if (m0 >= count) return;
    int off = offsets[e];
    int n0 = nt * 64;
    int mcnt = min(64, count - m0);
    int tid = threadIdx.x;

    __shared__ __align__(16) unsigned short As[2][64 * 64];   // 16 KB
    __shared__ __align__(16) char BgR[2][64 * 136];           // 17 KB
    __shared__ __align__(16) char BuR[2][64 * 136];           // 17 KB
    __shared__ int toks[64];
    if (tid < 64) toks[tid] = row_token[off + m0 + min(tid, mcnt - 1)];
    __syncthreads();

    int w = tid >> 6, l = tid & 63;
    int wr = w >> 1, wc = w & 1;
    int lr = l & 15, lh = l >> 4;
    int rA = w * 8 + (l >> 3);    // A staging row (0..31), +32 per issue
    int cA = l & 7;               // 16B chunk within 128B row
    int kq = tid >> 4;            // 0..15: k-quad of B micro-tile
    int nq = tid & 15;            // 0..15: n-quad of B micro-tile

    const float* wgF = wg + (size_t)e * HID * FINT + n0;
    const float* wuF = wu + (size_t)e * HID * FINT + n0;

    f32x4 gacc[2][2] = {};
    f32x4 uacc[2][2] = {};
    float4 gld[4], uld[4];

    auto LOADB = [&](int k0) {
        #pragma unroll
        for (int j = 0; j < 4; ++j) {
            size_t ro = (size_t)(k0 + kq * 4 + j) * FINT + nq * 4;
            gld[j] = *(const float4*)&wgF[ro];
            uld[j] = *(const float4*)&wuF[ro];
        }
    };

    auto WRITEB = [&](int buf) {
        char* bg = &BgR[buf][0];
        char* bu = &BuR[buf][0];
        #define WB_(i, comp) { \
            int r = nq * 4 + i; \
            int byte = r * 136 + kq * 8; \
            ushort4 og = make_ushort4(f2bf(gld[0].comp), f2bf(gld[1].comp), \
                                      f2bf(gld[2].comp), f2bf(gld[3].comp)); \
            ushort4 ou = make_ushort4(f2bf(uld[0].comp), f2bf(uld[1].comp), \
                                      f2bf(uld[2].comp), f2bf(uld[3].comp)); \
            *(uint2*)(bg + byte) = *(const uint2*)&og; \
            *(uint2*)(bu + byte) = *(const uint2*)&ou; }
        WB_(0, x) WB_(1, y) WB_(2, z) WB_(3, w)
        #undef WB_
    };

    auto STAGEA = [&](int buf, int k0) {
        #pragma unroll
        for (int i = 0; i < 2; ++i) {
            int row = 32 * i + rA;
            int sc = (cA ^ (row & 7)) << 3;
            size_t db = (size_t)(32 * i + w * 8) * 128;
            gl16(xb + (size_t)toks[row] * HID + k0 + sc, (char*)&As[buf][0] + db);
        }
    };

    auto COMPUTE = [&](int buf) {
        const char* bg = &BgR[buf][0];
        const char* bu = &BuR[buf][0];
        #pragma unroll
        for (int ks = 0; ks < 2; ++ks) {
            bf16x8 af[2], bgf[2], buf_[2];
            #pragma unroll
            for (int mi = 0; mi < 2; ++mi) {
                int row = wr * 32 + mi * 16 + lr;
                int byte = row * 128 + ((ks * 64 + lh * 16) ^ ((row & 7) << 4));
                af[mi] = *(const bf16x8*)((const char*)&As[buf][0] + byte);
            }
            #pragma unroll
            for (int ni = 0; ni < 2; ++ni) {
                int row = wc * 32 + ni * 16 + lr;
                int byte = row * 136 + ks * 64 + lh * 16;
                bf16x4 glo = *(const bf16x4*)(bg + byte);
                bf16x4 ghi = *(const bf16x4*)(bg + byte + 8);
                bf16x4 ulo = *(const bf16x4*)(bu + byte);
                bf16x4 uhi = *(const bf16x4*)(bu + byte + 8);
                bgf[ni] = __builtin_shufflevector(glo, ghi, 0, 1, 2, 3, 4, 5, 6, 7);
                buf_[ni] = __builtin_shufflevector(ulo, uhi, 0, 1, 2, 3, 4, 5, 6, 7);
            }
            #pragma unroll
            for (int mi = 0; mi < 2; ++mi)
                #pragma unroll
                for (int ni = 0; ni < 2; ++ni) {
                    gacc[mi][ni] = __builtin_amdgcn_mfma_f32_16x16x32_bf16(af[mi], bgf[ni], gacc[mi][ni], 0, 0, 0);
                    uacc[mi][ni] = __builtin_amdgcn_mfma_f32_16x16x32_bf16(af[mi], buf_[ni], uacc[mi][ni], 0, 0, 0);
                }
        }
    };

    // prologue
    LOADB(0);
    STAGEA(0, 0);
    WRITEB(0);
    __syncthreads();
    const int NT = HID / 64;
    for (int t = 0; t < NT; ++t) {
        int cur = t & 1;
        if (t + 1 < NT) {
            LOADB((t + 1) * 64);       // f32 loads in flight during COMPUTE
            STAGEA(cur ^ 1, (t + 1) * 64);
        }
        COMPUTE(cur);
        if (t + 1 < NT) WRITEB(cur ^ 1);  // loads landed under COMPUTE (T14)
        __syncthreads();
    }

    #pragma unroll
    for (int mi = 0; mi < 2; ++mi)
        #pragma unroll
        for (int ni = 0; ni < 2; ++ni)
            #pragma unroll
            for (int j = 0; j < 4; ++j) {
                int row = wr * 32 + mi * 16 + lh * 4 + j;
                if (row < mcnt) {
                    int col = wc * 32 + ni * 16 + lr;
                    float g = gacc[mi][ni][j], u = uacc[mi][ni][j];
                    float hv = g / (1.f + expf(-g)) * u;
                    h_buf[(size_t)(off + m0 + row) * FINT + n0 + col] = f2bf(hv);
                }
            }
}

// ---------------- MFMA stage B: out[tok] += w * (h * Wd) ----------------
__global__ __launch_bounds__(256) void moe_stage_b_mfma(
        const unsigned short* __restrict__ h_buf, // [4224][768]
        const unsigned short* __restrict__ wdt,   // [8][2048][768]
        const int* __restrict__ counts,
        const int* __restrict__ offsets,
        const int* __restrict__ row_token,
        const float* __restrict__ row_w,
        float* __restrict__ out) {
    int e = blockIdx.x, mt = blockIdx.y, nt = blockIdx.z;
    int count = counts[e];
    int m0 = mt * 128;
    if (m0 >= count) return;
    int off = offsets[e];
    int n0 = nt * 128;
    int mcnt = min(128, count - m0);
    int tid = threadIdx.x;

    __shared__ __align__(16) unsigned short As[2][128 * 64];  // 32 KB
    __shared__ __align__(16) unsigned short Bs[2][128 * 64];  // 32 KB
    __shared__ int toks[128];
    __shared__ float rws[128];
    if (tid < 128) {
        int mm = min(tid, mcnt - 1);
        toks[tid] = row_token[off + m0 + mm];
        rws[tid] = row_w[off + m0 + mm];
    }
    __syncthreads();

    int w = tid >> 6, l = tid & 63;
    int wr = w >> 1, wc = w & 1;
    int lr = l & 15, lh = l >> 4;
    int wbase = (tid & 192) * 16;

    const unsigned short* hb = h_buf + (size_t)(off + m0) * FINT;
    const unsigned short* wdE = wdt + (size_t)e * HID * FINT + (size_t)n0 * FINT;

    f32x4 acc[4][4] = {};

    auto STAGE = [&](int buf, int k0) {
        #pragma unroll
        for (int i = 0; i < 4; ++i) {
            int s = i * 256 + tid;
            int row = s >> 3, c = s & 7;
            int sc = (c ^ (row & 7)) << 3;
            gl16(hb + (size_t)row * FINT + k0 + sc,  (char*)&As[buf][0] + i * 4096 + wbase);
            gl16(wdE + (size_t)row * FINT + k0 + sc, (char*)&Bs[buf][0] + i * 4096 + wbase);
        }
    };

    auto COMPUTE = [&](int buf) {
        #pragma unroll
        for (int ks = 0; ks < 2; ++ks) {
            bf16x8 af[4], bf[4];
            #pragma unroll
            for (int mi = 0; mi < 4; ++mi) {
                int row = wr * 64 + mi * 16 + lr;
                int byte = row * 128 + ((ks * 64 + lh * 16) ^ ((row & 7) << 4));
                af[mi] = *(const bf16x8*)((const char*)&As[buf][0] + byte);
            }
            #pragma unroll
            for (int ni = 0; ni < 4; ++ni) {
                int row = wc * 64 + ni * 16 + lr;
                int byte = row * 128 + ((ks * 64 + lh * 16) ^ ((row & 7) << 4));
                bf[ni] = *(const bf16x8*)((const char*)&Bs[buf][0] + byte);
            }
            #pragma unroll
            for (int mi = 0; mi < 4; ++mi)
                #pragma unroll
                for (int ni = 0; ni < 4; ++ni)
                    acc[mi][ni] = __builtin_amdgcn_mfma_f32_16x16x32_bf16(af[mi], bf[ni], acc[mi][ni], 0, 0, 0);
        }
    };

    STAGE(0, 0);
    __syncthreads();
    for (int t = 0; t < FINT / 64; ++t) {
        int cur = t & 1;
        if (t + 1 < FINT / 64) STAGE(cur ^ 1, (t + 1) * 64);
        COMPUTE(cur);
        __syncthreads();
    }

    #pragma unroll
    for (int mi = 0; mi < 4; ++mi)
        #pragma unroll
        for (int ni = 0; ni < 4; ++ni)
            #pragma unroll
            for (int j = 0; j < 4; ++j) {
                int row = wr * 64 + mi * 16 + lh * 4 + j;
                if (row < mcnt) {
                    int col = n0 + wc * 64 + ni * 16 + lr;
                    atomicAdd(&out[(size_t)toks[row] * HID + col],
                              rws[row] * acc[mi][ni][j]);
                }
            }
}

extern "C" void kernel_launch(void* const* d_in, const int* in_sizes, int n_in,
                              void* d_out, int out_size, void* d_ws, size_t ws_size,
                              hipStream_t stream) {
    const float* x       = (const float*)d_in[0];  // [2,1024,2048]
    const float* gate_w  = (const float*)d_in[1];  // [8,2048]
    const float* w_gate  = (const float*)d_in[2];  // [8,2048,768]
    const float* w_up    = (const float*)d_in[3];  // [8,2048,768]
    const float* w_down  = (const float*)d_in[4];  // [8,768,2048]
    float* out = (float*)d_out;                    // 2048*2048 out + 2048*8 logits

    char* ws = (char*)d_ws;
    int*   topk_idx  = (int*)  (ws + 0);
    float* topk_w    = (float*)(ws + 16384);
    int*   counts    = (int*)  (ws + 32768);
    int*   offsets   = (int*)  (ws + 32800);
    int*   row_token = (int*)  (ws + 33024);
    float* row_w     = (float*)(ws + 49408);
    int*   elist_t   = (int*)  (ws + 65792);
    float* elist_w   = (float*)(ws + 131328);

    unsigned short* xb   = (unsigned short*)(ws + 196864);
    unsigned short* wd_t = (unsigned short*)(ws + 58917120);
    unsigned short* hb   = (unsigned short*)(ws + 84082944);

    float* logits_out = out + (size_t)NTOK * HID;

    k1_router_wd<<<512 + 3072, 256, 0, stream>>>(
        x, gate_w, w_down, out, logits_out, topk_idx, topk_w, xb, wd_t);
    moe_build_kernel<<<1, 1024, 0, stream>>>(topk_idx, topk_w, counts, offsets,
                                             elist_t, elist_w, row_token, row_w);
    dim3 gridA(NEXP, NTOK / 64, FINT / 64);
    moe_stage_a2<<<gridA, 256, 0, stream>>>(xb, w_gate, w_up, counts, offsets,
                                            row_token, hb);
    dim3 gridB(NEXP, NTOK / 128, HID / 128);
    moe_stage_b_mfma<<<gridB, 256, 0, stream>>>(hb, wd_t, counts, offsets,
                                                row_token, row_w, out);
}

// Round 12
// 148.805 us; speedup vs baseline: 1.2015x; 1.2015x over previous
//
#include <hip/hip_runtime.h>
#include <hip/hip_bf16.h>
#include <math.h>

#define NTOK 2048
#define HID 2048
#define NEXP 8
#define FINT 768
#define TOPK 2

typedef __attribute__((ext_vector_type(8))) short bf16x8;
typedef __attribute__((ext_vector_type(4))) float f32x4;

static __device__ __forceinline__ unsigned short f2bf(float f) {
    union { float f; unsigned u; } v; v.f = f;
    unsigned r = v.u + 0x7fffu + ((v.u >> 16) & 1u);
    return (unsigned short)(r >> 16);
}

static __device__ __forceinline__ void gl16(const void* g, void* l) {
    __builtin_amdgcn_global_load_lds(
        (const __attribute__((address_space(1))) unsigned int*)g,
        (__attribute__((address_space(3))) unsigned int*)(uintptr_t)l,
        16, 0, 0);
}

// ---------------- workspace layout (bytes) ----------------
// 0       : topk_idx  int[4096]
// 16384   : topk_w    f32[4096]
// 32768   : counts    int[8]
// 32800   : offsets   int[8]
// 33024   : row_token int[4096]
// 49408   : row_w     f32[4096]
// 65792   : elist_t   int[8*2048]
// 131328  : elist_w   f32[8*2048]
// 196864  : x_bf16    [2048][2048]        8388608
// 8585472 : wg_t      [8][768][2048] bf16 25165824
// 33751296: wu_t      [8][768][2048] bf16 25165824
// 58917120: wd_t      [8][2048][768] bf16 25165824
// 84082944: h_buf     [4224][768]    bf16 6488064   -> end 90571008

// ---------------- transpose tile body ----------------
// [R][C] f32 tile (r0,c0) -> [C][R] bf16. Vectorized, XOR-swizzled LDS.
static __device__ __forceinline__ void transpose_tile(
        const float* __restrict__ src, unsigned short* __restrict__ dst,
        int R, int C, int r0, int c0, float* tile, int tid) {
    {
        int rbase = tid >> 4;           // 0..15
        int ch = tid & 15;              // source 16B chunk (4 floats)
        #pragma unroll
        for (int i = 0; i < 4; ++i) {
            int row = i * 16 + rbase;
            float4 v = *(const float4*)&src[(size_t)(r0 + row) * C + c0 + ch * 4];
            int p = ch ^ (row & 15);    // swizzled chunk
            *(float4*)&tile[row * 64 + p * 4] = v;
        }
    }
    __syncthreads();
    {
        int r16 = (tid & 15) * 4;       // 4 tile rows
        int cg = tid >> 4;              // 4-col group 0..15
        float4 v[4];
        #pragma unroll
        for (int j = 0; j < 4; ++j) {
            int row = r16 + j;
            int p = cg ^ (row & 15);
            v[j] = *(const float4*)&tile[row * 64 + p * 4];
        }
        #pragma unroll
        for (int i = 0; i < 4; ++i) {
            float c0v = (i == 0) ? v[0].x : (i == 1) ? v[0].y : (i == 2) ? v[0].z : v[0].w;
            float c1v = (i == 0) ? v[1].x : (i == 1) ? v[1].y : (i == 2) ? v[1].z : v[1].w;
            float c2v = (i == 0) ? v[2].x : (i == 1) ? v[2].y : (i == 2) ? v[2].z : v[2].w;
            float c3v = (i == 0) ? v[3].x : (i == 1) ? v[3].y : (i == 2) ? v[3].z : v[3].w;
            ushort4 o = make_ushort4(f2bf(c0v), f2bf(c1v), f2bf(c2v), f2bf(c3v));
            *(uint2*)&dst[(size_t)(c0 + cg * 4 + i) * R + r0 + r16] = *(const uint2*)&o;
        }
    }
}

// ---------------- K1: router + x-cvt + out-zero  UNION  all 3 transposes ---
// blocks [0,512): router (4 tokens each; zeroes out rows; writes xb)
// blocks [512, 6656): wg/wu transpose tiles
// blocks [6656, 9728): wd transpose tiles
__global__ __launch_bounds__(256) void k1_all(
        const float* __restrict__ x,
        const float* __restrict__ gw,
        const float* __restrict__ wg, const float* __restrict__ wu,
        const float* __restrict__ wd,
        float* __restrict__ out,
        float* __restrict__ logits_out,
        int* __restrict__ topk_idx,
        float* __restrict__ topk_w,
        unsigned short* __restrict__ xb,
        unsigned short* __restrict__ wgt, unsigned short* __restrict__ wut,
        unsigned short* __restrict__ wdt) {
    __shared__ __align__(16) float tile[64 * 64];
    int bid = blockIdx.x;
    if (bid < 512) {
        int w = threadIdx.x >> 6, l = threadIdx.x & 63;
        int t = bid * 4 + w;
        const float4* xr = (const float4*)(x + (size_t)t * HID);
        unsigned short* xbr = xb + (size_t)t * HID;
        float4 v[8];
        #pragma unroll
        for (int i = 0; i < 8; ++i) v[i] = xr[i * 64 + l];
        #pragma unroll
        for (int i = 0; i < 8; ++i)
            *(ushort4*)&xbr[(i * 64 + l) * 4] =
                make_ushort4(f2bf(v[i].x), f2bf(v[i].y), f2bf(v[i].z), f2bf(v[i].w));
        {
            float4 z = make_float4(0.f, 0.f, 0.f, 0.f);
            float4* orow = (float4*)(out + (size_t)t * HID);
            #pragma unroll
            for (int i = 0; i < 8; ++i) orow[i * 64 + l] = z;
        }
        float acc[NEXP];
        #pragma unroll
        for (int e = 0; e < NEXP; ++e) {
            const float4* gr = (const float4*)(gw + (size_t)e * HID);
            float a = 0.f;
            #pragma unroll
            for (int i = 0; i < 8; ++i) {
                float4 g = gr[i * 64 + l];
                a += v[i].x * g.x + v[i].y * g.y + v[i].z * g.z + v[i].w * g.w;
            }
            acc[e] = a;
        }
        #pragma unroll
        for (int off = 32; off > 0; off >>= 1)
            #pragma unroll
            for (int e = 0; e < NEXP; ++e) acc[e] += __shfl_xor(acc[e], off);
        if (l == 0) {
            float m = -1e30f;
            #pragma unroll
            for (int i = 0; i < NEXP; ++i) m = fmaxf(m, acc[i]);
            float p[NEXP];
            #pragma unroll
            for (int i = 0; i < NEXP; ++i) p[i] = expf(acc[i] - m);
            int i0 = 0;
            #pragma unroll
            for (int i = 1; i < NEXP; ++i) if (p[i] > p[i0]) i0 = i;
            int i1 = (i0 == 0) ? 1 : 0;
            #pragma unroll
            for (int i = 0; i < NEXP; ++i) if (i != i0 && p[i] > p[i1]) i1 = i;
            float w0 = p[i0], w1 = p[i1], sw = w0 + w1;
            topk_idx[t * 2 + 0] = i0;
            topk_idx[t * 2 + 1] = i1;
            topk_w[t * 2 + 0] = w0 / sw;
            topk_w[t * 2 + 1] = w1 / sw;
            #pragma unroll
            for (int i = 0; i < NEXP; ++i) logits_out[(size_t)t * NEXP + i] = acc[i];
        }
    } else if (bid < 6656) {
        int idx = bid - 512;            // 0..6143
        int e = idx / 768, sub = idx % 768;
        const float* src; unsigned short* dst;
        if (sub < 384) { src = wg; dst = wgt; }
        else           { src = wu; dst = wut; sub -= 384; }
        int tr = sub / 12, tc = sub % 12;   // [2048][768]: 32 x 12 tiles
        src += (size_t)e * HID * FINT;
        dst += (size_t)e * HID * FINT;
        transpose_tile(src, dst, HID, FINT, tr * 64, tc * 64, tile, threadIdx.x);
    } else {
        int idx = bid - 6656;           // 0..3071
        int e = idx / 384, sub = idx % 384;
        int tr = sub / 32, tc = sub % 32;   // wd [768][2048]: 12 x 32 tiles
        transpose_tile(wd + (size_t)e * FINT * HID,
                       wdt + (size_t)e * FINT * HID,
                       FINT, HID, tr * 64, tc * 64, tile, threadIdx.x);
    }
}

__global__ void moe_build_kernel(const int* __restrict__ topk_idx,
                                 const float* __restrict__ topk_w,
                                 int* __restrict__ counts,
                                 int* __restrict__ offsets,
                                 int* __restrict__ elist_t,
                                 float* __restrict__ elist_w,
                                 int* __restrict__ row_token,
                                 float* __restrict__ row_w) {
    __shared__ int scnt[NEXP];
    __shared__ int soff[NEXP];
    int tid = threadIdx.x; // 1024
    if (tid < NEXP) scnt[tid] = 0;
    __syncthreads();
    for (int t = tid; t < NTOK; t += 1024) {
        #pragma unroll
        for (int k = 0; k < TOPK; ++k) {
            int e = topk_idx[t * 2 + k];
            float w = topk_w[t * 2 + k];
            int slot = atomicAdd(&scnt[e], 1);
            elist_t[e * NTOK + slot] = t;
            elist_w[e * NTOK + slot] = w;
        }
    }
    __syncthreads();
    if (tid == 0) {
        int o = 0;
        for (int e = 0; e < NEXP; ++e) {
            soff[e] = o; offsets[e] = o; counts[e] = scnt[e]; o += scnt[e];
        }
    }
    __syncthreads();
    for (int e = 0; e < NEXP; ++e) {
        int c = scnt[e], o = soff[e];
        for (int s = tid; s < c; s += 1024) {
            row_token[o + s] = elist_t[e * NTOK + s];
            row_w[o + s]     = elist_w[e * NTOK + s];
        }
    }
}

// ---------------- MFMA stage A: h = silu(x*Wg) * (x*Wu) ----------------
// 64x64 tile (g+u share A), BK=64, 4 waves 2x2, double-buffered prefetch.
// (Verified r6-r8 form, ~45us, 0 bank conflicts.)
__global__ __launch_bounds__(256) void moe_stage_a_mfma(
        const unsigned short* __restrict__ xb,    // [2048][2048]
        const unsigned short* __restrict__ wgt,   // [8][768][2048]
        const unsigned short* __restrict__ wut,   // [8][768][2048]
        const int* __restrict__ counts,
        const int* __restrict__ offsets,
        const int* __restrict__ row_token,
        unsigned short* __restrict__ h_buf) {     // [4224][768]
    int e = blockIdx.x, mt = blockIdx.y, nt = blockIdx.z;
    int count = counts[e];
    int m0 = mt * 64;
    if (m0 >= count) return;
    int off = offsets[e];
    int n0 = nt * 64;
    int mcnt = min(64, count - m0);
    int tid = threadIdx.x;

    __shared__ __align__(16) unsigned short As[2][64 * 64];
    __shared__ __align__(16) unsigned short Bg[2][64 * 64];
    __shared__ __align__(16) unsigned short Bu[2][64 * 64];
    __shared__ int toks[64];
    if (tid < 64) toks[tid] = row_token[off + m0 + min(tid, mcnt - 1)];
    __syncthreads();

    int w = tid >> 6, l = tid & 63;
    int wr = w >> 1, wc = w & 1;
    int lr = l & 15, lh = l >> 4;
    int rA = w * 8 + (l >> 3);    // staging row (0..31), +32 per issue
    int cA = l & 7;               // 16B chunk within 128B row

    const unsigned short* wgE = wgt + (size_t)e * FINT * HID + (size_t)n0 * HID;
    const unsigned short* wuE = wut + (size_t)e * FINT * HID + (size_t)n0 * HID;

    f32x4 gacc[2][2] = {};
    f32x4 uacc[2][2] = {};

    auto STAGE = [&](int buf, int k0) {
        #pragma unroll
        for (int i = 0; i < 2; ++i) {
            int row = 32 * i + rA;
            int sc = (cA ^ (row & 7)) << 3;      // pre-swizzled source offset
            size_t db = (size_t)(32 * i + w * 8) * 128;
            gl16(xb + (size_t)toks[row] * HID + k0 + sc, (char*)&As[buf][0] + db);
            gl16(wgE + (size_t)row * HID + k0 + sc,      (char*)&Bg[buf][0] + db);
            gl16(wuE + (size_t)row * HID + k0 + sc,      (char*)&Bu[buf][0] + db);
        }
    };

    auto COMPUTE = [&](int buf) {
        #pragma unroll
        for (int ks = 0; ks < 2; ++ks) {
            bf16x8 af[2], bg[2], bu[2];
            #pragma unroll
            for (int mi = 0; mi < 2; ++mi) {
                int row = wr * 32 + mi * 16 + lr;
                int byte = row * 128 + ((ks * 64 + lh * 16) ^ ((row & 7) << 4));
                af[mi] = *(const bf16x8*)((const char*)&As[buf][0] + byte);
            }
            #pragma unroll
            for (int ni = 0; ni < 2; ++ni) {
                int row = wc * 32 + ni * 16 + lr;
                int byte = row * 128 + ((ks * 64 + lh * 16) ^ ((row & 7) << 4));
                bg[ni] = *(const bf16x8*)((const char*)&Bg[buf][0] + byte);
                bu[ni] = *(const bf16x8*)((const char*)&Bu[buf][0] + byte);
            }
            #pragma unroll
            for (int mi = 0; mi < 2; ++mi)
                #pragma unroll
                for (int ni = 0; ni < 2; ++ni) {
                    gacc[mi][ni] = __builtin_amdgcn_mfma_f32_16x16x32_bf16(af[mi], bg[ni], gacc[mi][ni], 0, 0, 0);
                    uacc[mi][ni] = __builtin_amdgcn_mfma_f32_16x16x32_bf16(af[mi], bu[ni], uacc[mi][ni], 0, 0, 0);
                }
        }
    };

    STAGE(0, 0);
    __syncthreads();                   // drain buf0
    for (int t = 0; t < HID / 64; ++t) {
        int cur = t & 1;
        if (t + 1 < HID / 64) STAGE(cur ^ 1, (t + 1) * 64);  // prefetch next
        COMPUTE(cur);                  // overlap with in-flight loads
        __syncthreads();               // drain next-tile loads + guard reuse
    }

    #pragma unroll
    for (int mi = 0; mi < 2; ++mi)
        #pragma unroll
        for (int ni = 0; ni < 2; ++ni)
            #pragma unroll
            for (int j = 0; j < 4; ++j) {
                int row = wr * 32 + mi * 16 + lh * 4 + j;
                if (row < mcnt) {
                    int col = wc * 32 + ni * 16 + lr;
                    float g = gacc[mi][ni][j], u = uacc[mi][ni][j];
                    float hv = g / (1.f + expf(-g)) * u;
                    h_buf[(size_t)(off + m0 + row) * FINT + n0 + col] = f2bf(hv);
                }
            }
}

// ---------------- MFMA stage B: out[tok] += w * (h * Wd) ----------------
// m97 structure: 128x128 tile, BK=64, 4 waves 2x2, acc[4][4], double-buffered.
__global__ __launch_bounds__(256) void moe_stage_b_mfma(
        const unsigned short* __restrict__ h_buf, // [4224][768]
        const unsigned short* __restrict__ wdt,   // [8][2048][768]
        const int* __restrict__ counts,
        const int* __restrict__ offsets,
        const int* __restrict__ row_token,
        const float* __restrict__ row_w,
        float* __restrict__ out) {
    int e = blockIdx.x, mt = blockIdx.y, nt = blockIdx.z;
    int count = counts[e];
    int m0 = mt * 128;
    if (m0 >= count) return;
    int off = offsets[e];
    int n0 = nt * 128;
    int mcnt = min(128, count - m0);
    int tid = threadIdx.x;

    __shared__ __align__(16) unsigned short As[2][128 * 64];  // 32 KB
    __shared__ __align__(16) unsigned short Bs[2][128 * 64];  // 32 KB
    __shared__ int toks[128];
    __shared__ float rws[128];
    if (tid < 128) {
        int mm = min(tid, mcnt - 1);
        toks[tid] = row_token[off + m0 + mm];
        rws[tid] = row_w[off + m0 + mm];
    }
    __syncthreads();

    int w = tid >> 6, l = tid & 63;
    int wr = w >> 1, wc = w & 1;
    int lr = l & 15, lh = l >> 4;
    int wbase = (tid & 192) * 16;   // wave-uniform byte base within 4KB slab

    const unsigned short* hb = h_buf + (size_t)(off + m0) * FINT;
    const unsigned short* wdE = wdt + (size_t)e * HID * FINT + (size_t)n0 * FINT;

    f32x4 acc[4][4] = {};

    auto STAGE = [&](int buf, int k0) {
        #pragma unroll
        for (int i = 0; i < 4; ++i) {
            int s = i * 256 + tid;
            int row = s >> 3, c = s & 7;
            int sc = (c ^ (row & 7)) << 3;
            gl16(hb + (size_t)row * FINT + k0 + sc,  (char*)&As[buf][0] + i * 4096 + wbase);
            gl16(wdE + (size_t)row * FINT + k0 + sc, (char*)&Bs[buf][0] + i * 4096 + wbase);
        }
    };

    auto COMPUTE = [&](int buf) {
        #pragma unroll
        for (int ks = 0; ks < 2; ++ks) {
            bf16x8 af[4], bf[4];
            #pragma unroll
            for (int mi = 0; mi < 4; ++mi) {
                int row = wr * 64 + mi * 16 + lr;
                int byte = row * 128 + ((ks * 64 + lh * 16) ^ ((row & 7) << 4));
                af[mi] = *(const bf16x8*)((const char*)&As[buf][0] + byte);
            }
            #pragma unroll
            for (int ni = 0; ni < 4; ++ni) {
                int row = wc * 64 + ni * 16 + lr;
                int byte = row * 128 + ((ks * 64 + lh * 16) ^ ((row & 7) << 4));
                bf[ni] = *(const bf16x8*)((const char*)&Bs[buf][0] + byte);
            }
            #pragma unroll
            for (int mi = 0; mi < 4; ++mi)
                #pragma unroll
                for (int ni = 0; ni < 4; ++ni)
                    acc[mi][ni] = __builtin_amdgcn_mfma_f32_16x16x32_bf16(af[mi], bf[ni], acc[mi][ni], 0, 0, 0);
        }
    };

    STAGE(0, 0);
    __syncthreads();
    for (int t = 0; t < FINT / 64; ++t) {
        int cur = t & 1;
        if (t + 1 < FINT / 64) STAGE(cur ^ 1, (t + 1) * 64);
        COMPUTE(cur);
        __syncthreads();
    }

    #pragma unroll
    for (int mi = 0; mi < 4; ++mi)
        #pragma unroll
        for (int ni = 0; ni < 4; ++ni)
            #pragma unroll
            for (int j = 0; j < 4; ++j) {
                int row = wr * 64 + mi * 16 + lh * 4 + j;
                if (row < mcnt) {
                    int col = n0 + wc * 64 + ni * 16 + lr;
                    atomicAdd(&out[(size_t)toks[row] * HID + col],
                              rws[row] * acc[mi][ni][j]);
                }
            }
}

extern "C" void kernel_launch(void* const* d_in, const int* in_sizes, int n_in,
                              void* d_out, int out_size, void* d_ws, size_t ws_size,
                              hipStream_t stream) {
    const float* x       = (const float*)d_in[0];  // [2,1024,2048]
    const float* gate_w  = (const float*)d_in[1];  // [8,2048]
    const float* w_gate  = (const float*)d_in[2];  // [8,2048,768]
    const float* w_up    = (const float*)d_in[3];  // [8,2048,768]
    const float* w_down  = (const float*)d_in[4];  // [8,768,2048]
    float* out = (float*)d_out;                    // 2048*2048 out + 2048*8 logits

    char* ws = (char*)d_ws;
    int*   topk_idx  = (int*)  (ws + 0);
    float* topk_w    = (float*)(ws + 16384);
    int*   counts    = (int*)  (ws + 32768);
    int*   offsets   = (int*)  (ws + 32800);
    int*   row_token = (int*)  (ws + 33024);
    float* row_w     = (float*)(ws + 49408);
    int*   elist_t   = (int*)  (ws + 65792);
    float* elist_w   = (float*)(ws + 131328);

    unsigned short* xb   = (unsigned short*)(ws + 196864);
    unsigned short* wg_t = (unsigned short*)(ws + 8585472);
    unsigned short* wu_t = (unsigned short*)(ws + 33751296);
    unsigned short* wd_t = (unsigned short*)(ws + 58917120);
    unsigned short* hb   = (unsigned short*)(ws + 84082944);

    float* logits_out = out + (size_t)NTOK * HID;

    k1_all<<<9728, 256, 0, stream>>>(
        x, gate_w, w_gate, w_up, w_down, out, logits_out,
        topk_idx, topk_w, xb, wg_t, wu_t, wd_t);
    moe_build_kernel<<<1, 1024, 0, stream>>>(topk_idx, topk_w, counts, offsets,
                                             elist_t, elist_w, row_token, row_w);
    dim3 gridA(NEXP, NTOK / 64, FINT / 64);
    moe_stage_a_mfma<<<gridA, 256, 0, stream>>>(xb, wg_t, wu_t, counts, offsets,
                                                row_token, hb);
    dim3 gridB(NEXP, NTOK / 128, HID / 128);
    moe_stage_b_mfma<<<gridB, 256, 0, stream>>>(hb, wd_t, counts, offsets,
                                                row_token, row_w, out);
}